// Round 6
// baseline (1183.898 us; speedup 1.0000x reference)
//
#include <hip/hip_runtime.h>
#include <stdint.h>
#include <stddef.h>

// NASCell fused: new_m,new_c = gates(x@Wx, m_prev@Wm, c_prev)
// B=8192, I=H=1024, 8H=8192. Outputs fp32: new_m at [0,8.4M), new_c at [8.4M,16.8M).
//
// V6: V2's verified 16x16x32 3-pass math + fine-grained pipeline:
//  - 64 phases (kt x {x-half, m-half}), 4 x 16KB LDS buffers (same 64KB).
//  - counted s_waitcnt vmcnt(N) + raw s_barrier (never vmcnt(0) mid-loop):
//    3 half-tiles in flight. W derived from issue ledger:
//    steady outstanding at barrier = stage(p+1)4 + stage(p+2)4 + A-pre(8) = 16.
//    Tail: p61=16, p62=12, p63=8.
//  - A double-buffered in regs: x-phase prefetches m(kt); m-phase x(kt+1).
//    A issued BEFORE stage so compiler's positional A-wait never drains the
//    prefetch queue.
//  - setprio(1) around MFMA clusters.
// Accuracy bit-identical to V2 (same fragments, same MFMA order, same epilogue).
// ws: per-(hblk,kt,mat) 16KB half-tile at ((hblk*32+kt)*2+mat)*16384;
// within (shorts): hl*4096 + c*512 + n*32 + 2*(k2 ^ (((n>>1)&3)<<2)).

typedef _Float16 half8 __attribute__((ext_vector_type(8)));
typedef float f32x4 __attribute__((ext_vector_type(4)));
typedef float float4v __attribute__((ext_vector_type(4)));
typedef unsigned int u32;
typedef u32 u32x4 __attribute__((ext_vector_type(4)));

__device__ __forceinline__ float fsig(float x) { return 1.0f / (1.0f + __expf(-x)); }
__device__ __forceinline__ float ftanh(float x) { return 2.0f * fsig(2.0f * x) - 1.0f; }
__device__ __forceinline__ u32 packh(_Float16 a, _Float16 b) {
  union { u32 u; _Float16 h[2]; } p;
  p.h[0] = a; p.h[1] = b; return p.u;
}

__device__ __forceinline__ void gload16(const void* g, void* l) {
  __builtin_amdgcn_global_load_lds(
      (const __attribute__((address_space(1))) void*)g,
      (__attribute__((address_space(3))) void*)l, 16, 0, 0);
}

// ---------------------------------------------------------------------------
// prep_all: fused weight-prep (bid<2048) + A-split (bid>=2048).
// prep part: thread (mat,g,n) gathers 32 k of col (g*1024+hblk*16+n),
// emits hi/lo packed k-pair words with the V2-verified XOR swizzle into the
// per-(hblk,kt,mat) 16KB half-tile.
// ---------------------------------------------------------------------------
__global__ __launch_bounds__(256) void prep_all(
    const float* __restrict__ w_inputs, const float* __restrict__ w_m,
    const float4v* __restrict__ xin, const float4v* __restrict__ min,
    u32* __restrict__ wsB,
    half8* __restrict__ xhi, half8* __restrict__ xlo,
    half8* __restrict__ mhi, half8* __restrict__ mlo) {
  const int bid = blockIdx.x;
  const int tid = threadIdx.x;
  if (bid < 2048) {
    const int kt = bid & 31;
    const int hblk = bid >> 5;
    const int n = tid & 15;
    const int g = (tid >> 4) & 7;
    const int mat = tid >> 7;
    const float* w = mat ? w_m : w_inputs;
    const float* src = w + (size_t)kt * 32 * 8192 + (size_t)g * 1024 + hblk * 16 + n;
    const int kx4 = ((n >> 1) & 3) << 2;
    u32 hw[16], lw[16];
#pragma unroll
    for (int k2 = 0; k2 < 16; ++k2) {
      const float v0 = src[(size_t)(2 * k2) * 8192];
      const float v1 = src[(size_t)(2 * k2 + 1) * 8192];
      const _Float16 h0 = (_Float16)v0, h1 = (_Float16)v1;
      hw[k2 ^ kx4] = packh(h0, h1);
      lw[k2 ^ kx4] = packh((_Float16)(v0 - (float)h0), (_Float16)(v1 - (float)h1));
    }
    u32* dhi = wsB + ((size_t)(hblk * 32 + kt) * 2 + mat) * 4096 + g * 256 + n * 16;
    u32* dlo = dhi + 2048;
#pragma unroll
    for (int t4 = 0; t4 < 4; ++t4) {
      u32x4 a = {hw[t4 * 4], hw[t4 * 4 + 1], hw[t4 * 4 + 2], hw[t4 * 4 + 3]};
      *(u32x4*)(dhi + t4 * 4) = a;
      u32x4 b = {lw[t4 * 4], lw[t4 * 4 + 1], lw[t4 * 4 + 2], lw[t4 * 4 + 3]};
      *(u32x4*)(dlo + t4 * 4) = b;
    }
  } else {
    const int sid = bid - 2048;           // 0..8191
    const int which = sid >> 12;          // 0=x, 1=m
    const int bx = sid & 4095;
    const float4v* in = which ? min : xin;
    half8* hi = which ? mhi : xhi;
    half8* lo = which ? mlo : xlo;
    const size_t idx = (size_t)bx * 256 + tid;
    const float4v a = in[idx * 2];
    const float4v b = in[idx * 2 + 1];
    half8 h, l;
#pragma unroll
    for (int j = 0; j < 4; ++j) {
      const float v = a[j]; const _Float16 hv = (_Float16)v;
      h[j] = hv; l[j] = (_Float16)(v - (float)hv);
    }
#pragma unroll
    for (int j = 0; j < 4; ++j) {
      const float v = b[j]; const _Float16 hv = (_Float16)v;
      h[4 + j] = hv; l[4 + j] = (_Float16)(v - (float)hv);
    }
    hi[idx] = h; lo[idx] = l;
  }
}

// ---------------------------------------------------------------------------
// Main kernel V6: 256 threads (4 waves x 64 rows), 256 rows x 16 h-cols per
// block. 64 phases, 4x16KB LDS buffers, counted-vmcnt pipeline.
// ---------------------------------------------------------------------------

#define NAS_WAITBAR(Wlit)                                                  \
  do {                                                                     \
    asm volatile("s_waitcnt vmcnt(" #Wlit ")" ::: "memory");               \
    __builtin_amdgcn_s_barrier();                                          \
    __builtin_amdgcn_sched_barrier(0);                                     \
  } while (0)

#define NAS_STAGE(KT, MAT, SLOT)                                           \
  do {                                                                     \
    const char* s_ = wsb + (size_t)(((KT) * 2 + (MAT)) * 16384);           \
    char* d_ = ldsb + (SLOT) * 16384;                                      \
    gload16(s_, d_);                                                       \
    gload16(s_ + 4096, d_ + 4096);                                         \
    gload16(s_ + 8192, d_ + 8192);                                         \
    gload16(s_ + 12288, d_ + 12288);                                       \
  } while (0)

#define NAS_LOADX(KT)                                                      \
  do {                                                                     \
    _Pragma("unroll") for (int r_ = 0; r_ < 4; ++r_) {                     \
      axh[r_] = *(const half8*)(xhb + r_ * 16384 + (KT) * 32);             \
      axl[r_] = *(const half8*)(xlb + r_ * 16384 + (KT) * 32);             \
    }                                                                      \
  } while (0)

#define NAS_LOADM(KT)                                                      \
  do {                                                                     \
    _Pragma("unroll") for (int r_ = 0; r_ < 4; ++r_) {                     \
      amh[r_] = *(const half8*)(mhb + r_ * 16384 + (KT) * 32);             \
      aml[r_] = *(const half8*)(mlb + r_ * 16384 + (KT) * 32);             \
    }                                                                      \
  } while (0)

#define NAS_XPASS(SLOT)                                                    \
  do {                                                                     \
    const short* bb_ = lds_s + (SLOT) * 8192;                              \
    __builtin_amdgcn_s_setprio(1);                                         \
    _Pragma("unroll") for (int c_ = 0; c_ < 8; ++c_) {                     \
      const int bo_ = c_ * 512 + m16 * 32 + qsw;                           \
      const half8 bh_ = *(const half8*)(bb_ + bo_);                        \
      const half8 bl_ = *(const half8*)(bb_ + 4096 + bo_);                 \
      _Pragma("unroll") for (int r_ = 0; r_ < 4; ++r_) {                   \
        f32x4 t_ = acc[r_][c_];                                            \
        t_ = __builtin_amdgcn_mfma_f32_16x16x32_f16(axh[r_], bh_, t_, 0, 0, 0); \
        t_ = __builtin_amdgcn_mfma_f32_16x16x32_f16(axh[r_], bl_, t_, 0, 0, 0); \
        t_ = __builtin_amdgcn_mfma_f32_16x16x32_f16(axl[r_], bh_, t_, 0, 0, 0); \
        acc[r_][c_] = t_;                                                  \
      }                                                                    \
    }                                                                      \
    __builtin_amdgcn_s_setprio(0);                                         \
  } while (0)

#define NAS_MPASS(SLOT)                                                    \
  do {                                                                     \
    const short* bb_ = lds_s + (SLOT) * 8192;                              \
    __builtin_amdgcn_s_setprio(1);                                         \
    _Pragma("unroll") for (int c_ = 0; c_ < 8; ++c_) {                     \
      const int bo_ = c_ * 512 + m16 * 32 + qsw;                           \
      const half8 bh_ = *(const half8*)(bb_ + bo_);                        \
      const half8 bl_ = *(const half8*)(bb_ + 4096 + bo_);                 \
      const int tgt_ = (c_ == 3) ? 8 : c_;                                 \
      _Pragma("unroll") for (int r_ = 0; r_ < 4; ++r_) {                   \
        f32x4 t_ = acc[r_][tgt_];                                          \
        t_ = __builtin_amdgcn_mfma_f32_16x16x32_f16(amh[r_], bh_, t_, 0, 0, 0); \
        t_ = __builtin_amdgcn_mfma_f32_16x16x32_f16(amh[r_], bl_, t_, 0, 0, 0); \
        t_ = __builtin_amdgcn_mfma_f32_16x16x32_f16(aml[r_], bh_, t_, 0, 0, 0); \
        acc[r_][tgt_] = t_;                                                \
      }                                                                    \
    }                                                                      \
    __builtin_amdgcn_s_setprio(0);                                         \
  } while (0)

__global__ __launch_bounds__(256, 2) void nascell_v6(
    const _Float16* __restrict__ xh_g, const _Float16* __restrict__ xl_g,
    const _Float16* __restrict__ mh_g, const _Float16* __restrict__ ml_g,
    const char* __restrict__ wsB,
    const float* __restrict__ c_prev,
    float* __restrict__ out) {
  __shared__ short lds_s[32768];  // 4 x 16KB half-tile buffers
  const int tid = threadIdx.x;
  const int wid = tid >> 6;
  const int lane = tid & 63;
  const int row0 = blockIdx.y * 256;
  const int hblk = blockIdx.x;
  const int m16 = lane & 15;
  const int q = lane >> 4;
  const int qsw = (q ^ ((m16 >> 1) & 3)) * 8;

  const _Float16* xhb = xh_g + (size_t)(row0 + wid * 64 + m16) * 1024 + q * 8;
  const _Float16* xlb = xl_g + (size_t)(row0 + wid * 64 + m16) * 1024 + q * 8;
  const _Float16* mhb = mh_g + (size_t)(row0 + wid * 64 + m16) * 1024 + q * 8;
  const _Float16* mlb = ml_g + (size_t)(row0 + wid * 64 + m16) * 1024 + q * 8;

  const char* wsb = wsB + (size_t)hblk * 1048576 + tid * 16;
  char* ldsb = (char*)lds_s + tid * 16;

  f32x4 acc[4][9];
#pragma unroll
  for (int r = 0; r < 4; ++r)
#pragma unroll
    for (int gg = 0; gg < 9; ++gg) acc[r][gg] = (f32x4)0.0f;

  half8 axh[4], axl[4], amh[4], aml[4];

  // prologue: stage phases 0,1,2; load ax(0). Outstanding at first barrier:
  // stage0(4)+stage1(4)+stage2(4)+ax0(8)=20; need stage0 -> vmcnt(16).
  NAS_STAGE(0, 0, 0);
  NAS_STAGE(0, 1, 1);
  NAS_STAGE(1, 0, 2);
  NAS_LOADX(0);

#pragma unroll 1
  for (int ktp = 0; ktp < 15; ++ktp) {
    const int kt0 = 2 * ktp, kt1 = 2 * ktp + 1;
    const int kt2 = 2 * ktp + 2, kt3 = 2 * ktp + 3;
    // phase 4ktp+0: x(kt0) from buf0; prefetch am(kt0); stage (kt1,m)->buf3
    NAS_WAITBAR(16); NAS_LOADM(kt0); NAS_STAGE(kt1, 1, 3); NAS_XPASS(0);
    // phase +1: m(kt0) buf1; prefetch ax(kt1); stage (kt2,x)->buf0
    NAS_WAITBAR(16); NAS_LOADX(kt1); NAS_STAGE(kt2, 0, 0); NAS_MPASS(1);
    // phase +2: x(kt1) buf2; prefetch am(kt1); stage (kt2,m)->buf1
    NAS_WAITBAR(16); NAS_LOADM(kt1); NAS_STAGE(kt2, 1, 1); NAS_XPASS(2);
    // phase +3: m(kt1) buf3; prefetch ax(kt2); stage (kt3,x)->buf2
    NAS_WAITBAR(16); NAS_LOADX(kt2); NAS_STAGE(kt3, 0, 2); NAS_MPASS(3);
  }
  // tail: kt=30,31 (phases 60..63)
  NAS_WAITBAR(16); NAS_LOADM(30); NAS_STAGE(31, 1, 3); NAS_XPASS(0);
  NAS_WAITBAR(16); NAS_LOADX(31); NAS_MPASS(1);
  NAS_WAITBAR(12); NAS_LOADM(31); NAS_XPASS(2);
  NAS_WAITBAR(8);  NAS_MPASS(3);

  // ---- epilogue (V2-verified, unchanged) ----
  float* out_m = out;
  float* out_c = out + (size_t)8192 * 1024;
  const int h = hblk * 16 + m16;
#pragma unroll
  for (int r = 0; r < 4; ++r) {
#pragma unroll
    for (int i = 0; i < 4; ++i) {
      const int grow = row0 + wid * 64 + r * 16 + q * 4 + i;
      const float p0 = acc[r][0][i], p1 = acc[r][1][i], p2 = acc[r][2][i];
      const float x3 = acc[r][3][i], p4 = acc[r][4][i], p5 = acc[r][5][i];
      const float p6 = acc[r][6][i], p7 = acc[r][7][i], m3 = acc[r][8][i];
      const float cp = c_prev[(size_t)grow * 1024 + h];
      float l1_0 = fsig(p0);
      float l1_1 = fmaxf(p1, 0.0f);
      float l1_2 = fsig(p2);
      float l1_3 = fmaxf(x3 * m3, 0.0f);
      float l1_4 = ftanh(p4);
      float l1_5 = fsig(p5);
      float l1_6 = ftanh(p6);
      float l1_7 = fsig(p7);
      float l2_0 = ftanh(l1_0 * l1_1);
      float l2_1 = ftanh(l1_2 + l1_3);
      float l2_2 = ftanh(l1_4 * l1_5);
      float l2_3 = fsig(l1_6 + l1_7);
      float l2_0b = ftanh(l2_0 + cp);
      float nc = l2_0b * l2_1;
      float l3_1 = ftanh(l2_2 + l2_3);
      float nm = ftanh(nc * l3_1);
      out_m[(size_t)grow * 1024 + h] = nm;
      out_c[(size_t)grow * 1024 + h] = nc;
    }
  }
}

// ---------------------------------------------------------------------------
// Legacy kernel (V1) — fallback when ws_size < 128 MB. Unchanged.
// ---------------------------------------------------------------------------
__global__ __launch_bounds__(256, 2) void nascell_main(
    const float* __restrict__ x,
    const float* __restrict__ m_prev,
    const float* __restrict__ c_prev,
    const float* __restrict__ w_inputs,
    const float* __restrict__ w_m,
    float* __restrict__ out) {
  __shared__ short lds[17408];
  const int tid = threadIdx.x;
  const int wid = tid >> 6;
  const int lane = tid & 63;
  const int row0 = blockIdx.y * 256;
  const int h0 = blockIdx.x * 16;
  const int m16 = lane & 15;
  const int q = lane >> 4;

  const int bmat = tid >> 7;
  const int bg = (tid >> 4) & 7;
  const int bkp = (tid & 15) * 2;
  const float* wsrc = bmat ? w_m : w_inputs;
  const float* wrow_base = wsrc + (size_t)bkp * 8192 + (size_t)bg * 1024 + (size_t)h0;
  short* bh = lds + bmat * 4352 + bg * 544 + (bkp ^ ((bg & 3) << 3));
  short* bl = bh + 8704;

  const float* axp[4];
  const float* amp[4];
#pragma unroll
  for (int r = 0; r < 4; ++r) {
    const size_t arow = (size_t)(row0 + wid * 64 + r * 16 + m16);
    axp[r] = x + arow * 1024 + q * 8;
    amp[r] = m_prev + arow * 1024 + q * 8;
  }

  f32x4 acc[4][9];
#pragma unroll
  for (int r = 0; r < 4; ++r)
#pragma unroll
    for (int gg = 0; gg < 9; ++gg) acc[r][gg] = (f32x4)0.0f;

  for (int kt = 0; kt < 32; ++kt) {
    const float* wr = wrow_base + (size_t)kt * 32 * 8192;
    float4v b0 = *(const float4v*)(wr);
    float4v b1 = *(const float4v*)(wr + 4);
    float4v b2 = *(const float4v*)(wr + 8);
    float4v b3 = *(const float4v*)(wr + 12);
    float4v d0 = *(const float4v*)(wr + 8192);
    float4v d1 = *(const float4v*)(wr + 8196);
    float4v d2 = *(const float4v*)(wr + 8200);
    float4v d3 = *(const float4v*)(wr + 8204);

    float4v xa[4][2];
#pragma unroll
    for (int r = 0; r < 4; ++r) {
      xa[r][0] = *(const float4v*)(axp[r] + kt * 32);
      xa[r][1] = *(const float4v*)(axp[r] + kt * 32 + 4);
    }

    __syncthreads();

#pragma unroll
    for (int n = 0; n < 16; ++n) {
      const float r0 = (n < 4 ? b0[n & 3] : n < 8 ? b1[n & 3] : n < 12 ? b2[n & 3] : b3[n & 3]);
      const float r1 = (n < 4 ? d0[n & 3] : n < 8 ? d1[n & 3] : n < 12 ? d2[n & 3] : d3[n & 3]);
      const _Float16 h0v = (_Float16)r0;
      const _Float16 h1v = (_Float16)r1;
      *(u32*)(bh + n * 32) = packh(h0v, h1v);
      const _Float16 l0v = (_Float16)(r0 - (float)h0v);
      const _Float16 l1v = (_Float16)(r1 - (float)h1v);
      *(u32*)(bl + n * 32) = packh(l0v, l1v);
    }

    half8 axh[4], axl[4];
#pragma unroll
    for (int r = 0; r < 4; ++r)
#pragma unroll
      for (int j = 0; j < 8; ++j) {
        const float v = xa[r][j >> 2][j & 3];
        const _Float16 hv = (_Float16)v;
        axh[r][j] = hv;
        axl[r][j] = (_Float16)(v - (float)hv);
      }

    __syncthreads();

    float4v ma[4][2];
#pragma unroll
    for (int r = 0; r < 4; ++r) {
      ma[r][0] = *(const float4v*)(amp[r] + kt * 32);
      ma[r][1] = *(const float4v*)(amp[r] + kt * 32 + 4);
    }

#pragma unroll
    for (int c = 0; c < 8; ++c) {
      const int qs = (q ^ (c & 3)) * 8;
      const int bo = c * 544 + m16 * 32 + qs;
      half8 bxh = *(const half8*)(lds + bo);
      half8 bxl = *(const half8*)(lds + 8704 + bo);
#pragma unroll
      for (int r = 0; r < 4; ++r) {
        f32x4 t = acc[r][c];
        t = __builtin_amdgcn_mfma_f32_16x16x32_f16(axh[r], bxh, t, 0, 0, 0);
        t = __builtin_amdgcn_mfma_f32_16x16x32_f16(axh[r], bxl, t, 0, 0, 0);
        t = __builtin_amdgcn_mfma_f32_16x16x32_f16(axl[r], bxh, t, 0, 0, 0);
        acc[r][c] = t;
      }
    }

    half8 amh[4], aml[4];
#pragma unroll
    for (int r = 0; r < 4; ++r)
#pragma unroll
      for (int j = 0; j < 8; ++j) {
        const float v = ma[r][j >> 2][j & 3];
        const _Float16 hv = (_Float16)v;
        amh[r][j] = hv;
        aml[r][j] = (_Float16)(v - (float)hv);
      }

#pragma unroll
    for (int c = 0; c < 8; ++c) {
      const int qs = (q ^ (c & 3)) * 8;
      const int bo = 4352 + c * 544 + m16 * 32 + qs;
      half8 bmh = *(const half8*)(lds + bo);
      half8 bml = *(const half8*)(lds + 8704 + bo);
      const int tgt = (c == 3) ? 8 : c;
#pragma unroll
      for (int r = 0; r < 4; ++r) {
        f32x4 t = acc[r][tgt];
        t = __builtin_amdgcn_mfma_f32_16x16x32_f16(amh[r], bmh, t, 0, 0, 0);
        t = __builtin_amdgcn_mfma_f32_16x16x32_f16(amh[r], bml, t, 0, 0, 0);
        t = __builtin_amdgcn_mfma_f32_16x16x32_f16(aml[r], bmh, t, 0, 0, 0);
        acc[r][tgt] = t;
      }
    }
  }

  float* out_m = out;
  float* out_c = out + (size_t)8192 * 1024;
  const int h = h0 + m16;
#pragma unroll
  for (int r = 0; r < 4; ++r) {
#pragma unroll
    for (int i = 0; i < 4; ++i) {
      const int grow = row0 + wid * 64 + r * 16 + q * 4 + i;
      const float p0 = acc[r][0][i], p1 = acc[r][1][i], p2 = acc[r][2][i];
      const float x3 = acc[r][3][i], p4 = acc[r][4][i], p5 = acc[r][5][i];
      const float p6 = acc[r][6][i], p7 = acc[r][7][i], m3 = acc[r][8][i];
      const float cp = c_prev[(size_t)grow * 1024 + h];
      float l1_0 = fsig(p0);
      float l1_1 = fmaxf(p1, 0.0f);
      float l1_2 = fsig(p2);
      float l1_3 = fmaxf(x3 * m3, 0.0f);
      float l1_4 = ftanh(p4);
      float l1_5 = fsig(p5);
      float l1_6 = ftanh(p6);
      float l1_7 = fsig(p7);
      float l2_0 = ftanh(l1_0 * l1_1);
      float l2_1 = ftanh(l1_2 + l1_3);
      float l2_2 = ftanh(l1_4 * l1_5);
      float l2_3 = fsig(l1_6 + l1_7);
      float l2_0b = ftanh(l2_0 + cp);
      float nc = l2_0b * l2_1;
      float l3_1 = ftanh(l2_2 + l2_3);
      float nm = ftanh(nc * l3_1);
      out_m[(size_t)grow * 1024 + h] = nm;
      out_c[(size_t)grow * 1024 + h] = nc;
    }
  }
}

extern "C" void kernel_launch(void* const* d_in, const int* in_sizes, int n_in,
                              void* d_out, int out_size, void* d_ws, size_t ws_size,
                              hipStream_t stream) {
  (void)in_sizes; (void)n_in; (void)out_size;
  const float* x        = (const float*)d_in[0];
  const float* m_prev   = (const float*)d_in[1];
  const float* c_prev   = (const float*)d_in[2];
  const float* w_m      = (const float*)d_in[3];
  const float* w_inputs = (const float*)d_in[4];
  float* out = (float*)d_out;

  // ws layout: [0,64MB) B half-tiles; then xh,xl,mh,ml (16MB each) = 128MB.
  if (ws_size >= 134217728ull && d_ws != nullptr) {
    u32* wsB = (u32*)d_ws;
    _Float16* xh = (_Float16*)((char*)d_ws + 67108864);
    _Float16* xl = xh + 8388608;
    _Float16* mh = xl + 8388608;
    _Float16* ml = mh + 8388608;
    prep_all<<<10240, 256, 0, stream>>>(
        w_inputs, w_m, (const float4v*)x, (const float4v*)m_prev, wsB,
        (half8*)xh, (half8*)xl, (half8*)mh, (half8*)ml);
    nascell_v6<<<dim3(64, 32), 256, 0, stream>>>(
        xh, xl, mh, ml, (const char*)d_ws, c_prev, out);
  } else {
    dim3 grid(64, 32);
    nascell_main<<<grid, 256, 0, stream>>>(x, m_prev, c_prev, w_inputs, w_m, out);
  }
}

// Round 7
// 1035.346 us; speedup vs baseline: 1.1435x; 1.1435x over previous
//
#include <hip/hip_runtime.h>
#include <stdint.h>
#include <stddef.h>

// NASCell fused: new_m,new_c = gates(x@Wx, m_prev@Wm, c_prev)
// B=8192, I=H=1024, 8H=8192. Outputs fp32: new_m at [0,8.4M), new_c at [8.4M,16.8M).
//
// V7: LLC-traffic-optimized retile of V2's verified math.
//  Diagnosis: V2 (740us) sits at its MFMA *demand* ceiling (2 waves/SIMD x 27%
//  duty = 54%; measured 52.7). The kt period is set by LLC stream bandwidth:
//  A(4GB)+B(2GB) = 6GB total. Traffic = 64MB*(1024/C) + 64MB*(8192/R).
//  V7 widens the block tile to 256 rows x 32 cols -> 2GB + 2GB = 4GB (-33%).
//  - 512 threads, 8 waves = 4 rowgroups x 2 colgroups; EACH WAVE'S CODE IS
//    BYTE-EQUIVALENT TO V2's (64x16 tile, acc[4][9], 3-pass hh/hl/lh) -> no
//    new register pressure (V3/V4/V6 spills all came from changing this).
//  - LDS 2 x 32KB: buf0 = x-half (both colgroups), buf1 = m-half. Per phase:
//    barrier -> stage other half (global_load_lds,16B) + prefetch next A-frags
//    -> 96 MFMAs. All drained loads are a full phase (~4K cyc) old.
//  - 1 block/CU, grid (32,32), 4 generations.
// prep_all is byte-identical to V6 (HW-verified: V6 passed, absmax 0.00390625;
// per-(hblk16,kt,mat) 16KB half-tile images with the XOR k-swizzle).

typedef _Float16 half8 __attribute__((ext_vector_type(8)));
typedef float f32x4 __attribute__((ext_vector_type(4)));
typedef float float4v __attribute__((ext_vector_type(4)));
typedef unsigned int u32;
typedef u32 u32x4 __attribute__((ext_vector_type(4)));

__device__ __forceinline__ float fsig(float x) { return 1.0f / (1.0f + __expf(-x)); }
__device__ __forceinline__ float ftanh(float x) { return 2.0f * fsig(2.0f * x) - 1.0f; }
__device__ __forceinline__ u32 packh(_Float16 a, _Float16 b) {
  union { u32 u; _Float16 h[2]; } p;
  p.h[0] = a; p.h[1] = b; return p.u;
}

__device__ __forceinline__ void gload16(const void* g, void* l) {
  __builtin_amdgcn_global_load_lds(
      (const __attribute__((address_space(1))) void*)g,
      (__attribute__((address_space(3))) void*)l, 16, 0, 0);
}

// ---------------------------------------------------------------------------
// prep_all: fused weight-prep (bid<2048) + A-split (bid>=2048). [V6-verified]
// ---------------------------------------------------------------------------
__global__ __launch_bounds__(256) void prep_all(
    const float* __restrict__ w_inputs, const float* __restrict__ w_m,
    const float4v* __restrict__ xin, const float4v* __restrict__ min,
    u32* __restrict__ wsB,
    half8* __restrict__ xhi, half8* __restrict__ xlo,
    half8* __restrict__ mhi, half8* __restrict__ mlo) {
  const int bid = blockIdx.x;
  const int tid = threadIdx.x;
  if (bid < 2048) {
    const int kt = bid & 31;
    const int hblk = bid >> 5;
    const int n = tid & 15;
    const int g = (tid >> 4) & 7;
    const int mat = tid >> 7;
    const float* w = mat ? w_m : w_inputs;
    const float* src = w + (size_t)kt * 32 * 8192 + (size_t)g * 1024 + hblk * 16 + n;
    const int kx4 = ((n >> 1) & 3) << 2;
    u32 hw[16], lw[16];
#pragma unroll
    for (int k2 = 0; k2 < 16; ++k2) {
      const float v0 = src[(size_t)(2 * k2) * 8192];
      const float v1 = src[(size_t)(2 * k2 + 1) * 8192];
      const _Float16 h0 = (_Float16)v0, h1 = (_Float16)v1;
      hw[k2 ^ kx4] = packh(h0, h1);
      lw[k2 ^ kx4] = packh((_Float16)(v0 - (float)h0), (_Float16)(v1 - (float)h1));
    }
    u32* dhi = wsB + ((size_t)(hblk * 32 + kt) * 2 + mat) * 4096 + g * 256 + n * 16;
    u32* dlo = dhi + 2048;
#pragma unroll
    for (int t4 = 0; t4 < 4; ++t4) {
      u32x4 a = {hw[t4 * 4], hw[t4 * 4 + 1], hw[t4 * 4 + 2], hw[t4 * 4 + 3]};
      *(u32x4*)(dhi + t4 * 4) = a;
      u32x4 b = {lw[t4 * 4], lw[t4 * 4 + 1], lw[t4 * 4 + 2], lw[t4 * 4 + 3]};
      *(u32x4*)(dlo + t4 * 4) = b;
    }
  } else {
    const int sid = bid - 2048;           // 0..8191
    const int which = sid >> 12;          // 0=x, 1=m
    const int bx = sid & 4095;
    const float4v* in = which ? min : xin;
    half8* hi = which ? mhi : xhi;
    half8* lo = which ? mlo : xlo;
    const size_t idx = (size_t)bx * 256 + tid;
    const float4v a = in[idx * 2];
    const float4v b = in[idx * 2 + 1];
    half8 h, l;
#pragma unroll
    for (int j = 0; j < 4; ++j) {
      const float v = a[j]; const _Float16 hv = (_Float16)v;
      h[j] = hv; l[j] = (_Float16)(v - (float)hv);
    }
#pragma unroll
    for (int j = 0; j < 4; ++j) {
      const float v = b[j]; const _Float16 hv = (_Float16)v;
      h[4 + j] = hv; l[4 + j] = (_Float16)(v - (float)hv);
    }
    hi[idx] = h; lo[idx] = l;
  }
}

// ---------------------------------------------------------------------------
// Main kernel V7: 512 threads (8 waves = 4 rowgrp x 2 colgrp), block tile
// 256 rows x 32 h-cols. Per wave: V2's exact 64x16 pass structure.
// LDS: buf0 (bytes [0,32768)) = x-half {cg0,cg1}; buf1 ([32768,65536)) = m-half.
// ---------------------------------------------------------------------------

#define NAS_STG(KT, MAT, BUFB)                                              \
  do {                                                                      \
    const char* s_ = (const char*)wsB +                                     \
        (((size_t)(2 * hb2 + cgs) * 32 + (size_t)(KT)) * 2 + (MAT)) * 16384 \
        + tg * 16;                                                          \
    char* d_ = ldsc + (BUFB) + cgs * 16384 + tg * 16;                       \
    gload16(s_, d_);                                                        \
    gload16(s_ + 4096, d_ + 4096);                                          \
    gload16(s_ + 8192, d_ + 8192);                                          \
    gload16(s_ + 12288, d_ + 12288);                                        \
  } while (0)

#define NAS_LOADX(KT)                                                       \
  do {                                                                      \
    _Pragma("unroll") for (int r_ = 0; r_ < 4; ++r_) {                      \
      axh[r_] = *(const half8*)(xhb + r_ * 16384 + (KT) * 32);              \
      axl[r_] = *(const half8*)(xlb + r_ * 16384 + (KT) * 32);              \
    }                                                                       \
  } while (0)

#define NAS_LOADM(KT)                                                       \
  do {                                                                      \
    _Pragma("unroll") for (int r_ = 0; r_ < 4; ++r_) {                      \
      amh[r_] = *(const half8*)(mhb + r_ * 16384 + (KT) * 32);              \
      aml[r_] = *(const half8*)(mlb + r_ * 16384 + (KT) * 32);              \
    }                                                                       \
  } while (0)

__global__ __launch_bounds__(512, 2) void nascell_v7(
    const _Float16* __restrict__ xh_g, const _Float16* __restrict__ xl_g,
    const _Float16* __restrict__ mh_g, const _Float16* __restrict__ ml_g,
    const u32* __restrict__ wsB,
    const float* __restrict__ c_prev,
    float* __restrict__ out) {
  __shared__ short lds_s[32768];  // 64KB: buf0 x-half, buf1 m-half
  char* ldsc = (char*)lds_s;
  const int tid = threadIdx.x;
  const int wid = tid >> 6;
  const int lane = tid & 63;
  const int wr = wid >> 1;        // rowgroup 0..3
  const int cg = wid & 1;         // colgroup 0..1
  const int row0 = blockIdx.y * 256;
  const int hb2 = blockIdx.x;     // 0..31 (pairs of 16-col hblks)
  const int m16 = lane & 15;
  const int q = lane >> 4;
  const int qsw = (q ^ ((m16 >> 1) & 3)) * 8;  // shorts

  // staging decomposition: threads [0,256) stage cg 0, [256,512) cg 1
  const int tg = tid & 255;
  const int cgs = tid >> 8;

  const _Float16* xhb = xh_g + (size_t)(row0 + wr * 64 + m16) * 1024 + q * 8;
  const _Float16* xlb = xl_g + (size_t)(row0 + wr * 64 + m16) * 1024 + q * 8;
  const _Float16* mhb = mh_g + (size_t)(row0 + wr * 64 + m16) * 1024 + q * 8;
  const _Float16* mlb = ml_g + (size_t)(row0 + wr * 64 + m16) * 1024 + q * 8;

  f32x4 acc[4][9];
#pragma unroll
  for (int r = 0; r < 4; ++r)
#pragma unroll
    for (int gg = 0; gg < 9; ++gg) acc[r][gg] = (f32x4)0.0f;

  half8 axh[4], axl[4], amh[4], aml[4];

  // wave's LDS read bases (shorts): x-half at cg*8192, m-half at 16384+cg*8192
  const short* bbx = lds_s + cg * 8192;
  const short* bbm = lds_s + 16384 + cg * 8192;

  // prologue: stage (0,x) -> buf0; load A-x(0)
  NAS_STG(0, 0, 0);
  NAS_LOADX(0);

#pragma unroll 1
  for (int kt = 0; kt < 32; ++kt) {
    // ---------- x phase: buf0 ----------
    __syncthreads();  // drains stage(kt,x) + ax(kt) (both a full phase old)
    NAS_STG(kt, 1, 32768);   // stage m-half -> buf1
    NAS_LOADM(kt);           // prefetch A-m(kt), lands during x-pass
    __builtin_amdgcn_sched_barrier(0);
#pragma unroll
    for (int c = 0; c < 8; ++c) {
      const int bo = c * 512 + m16 * 32 + qsw;
      const half8 bh = *(const half8*)(bbx + bo);
      const half8 bl = *(const half8*)(bbx + 4096 + bo);
#pragma unroll
      for (int r = 0; r < 4; ++r) {
        f32x4 t = acc[r][c];
        t = __builtin_amdgcn_mfma_f32_16x16x32_f16(axh[r], bh, t, 0, 0, 0);
        t = __builtin_amdgcn_mfma_f32_16x16x32_f16(axh[r], bl, t, 0, 0, 0);
        t = __builtin_amdgcn_mfma_f32_16x16x32_f16(axl[r], bh, t, 0, 0, 0);
        acc[r][c] = t;
      }
    }
    // ---------- m phase: buf1 ----------
    __syncthreads();  // drains stage(kt,m) + am(kt) (issued at x-phase start)
    if (kt < 31) {
      NAS_STG(kt + 1, 0, 0);  // stage next x-half -> buf0
      NAS_LOADX(kt + 1);      // prefetch A-x(kt+1)
    }
    __builtin_amdgcn_sched_barrier(0);
#pragma unroll
    for (int c = 0; c < 8; ++c) {
      const int bo = c * 512 + m16 * 32 + qsw;
      const half8 bh = *(const half8*)(bbm + bo);
      const half8 bl = *(const half8*)(bbm + 4096 + bo);
      const int tgt = (c == 3) ? 8 : c;
#pragma unroll
      for (int r = 0; r < 4; ++r) {
        f32x4 t = acc[r][tgt];
        t = __builtin_amdgcn_mfma_f32_16x16x32_f16(amh[r], bh, t, 0, 0, 0);
        t = __builtin_amdgcn_mfma_f32_16x16x32_f16(amh[r], bl, t, 0, 0, 0);
        t = __builtin_amdgcn_mfma_f32_16x16x32_f16(aml[r], bh, t, 0, 0, 0);
        acc[r][tgt] = t;
      }
    }
  }

  // ---- epilogue (V2-verified formulas) ----
  float* out_m = out;
  float* out_c = out + (size_t)8192 * 1024;
  const int h = hb2 * 32 + cg * 16 + m16;
#pragma unroll
  for (int r = 0; r < 4; ++r) {
#pragma unroll
    for (int i = 0; i < 4; ++i) {
      const int grow = row0 + wr * 64 + r * 16 + q * 4 + i;
      const float p0 = acc[r][0][i], p1 = acc[r][1][i], p2 = acc[r][2][i];
      const float x3 = acc[r][3][i], p4 = acc[r][4][i], p5 = acc[r][5][i];
      const float p6 = acc[r][6][i], p7 = acc[r][7][i], m3 = acc[r][8][i];
      const float cp = c_prev[(size_t)grow * 1024 + h];
      float l1_0 = fsig(p0);
      float l1_1 = fmaxf(p1, 0.0f);
      float l1_2 = fsig(p2);
      float l1_3 = fmaxf(x3 * m3, 0.0f);
      float l1_4 = ftanh(p4);
      float l1_5 = fsig(p5);
      float l1_6 = ftanh(p6);
      float l1_7 = fsig(p7);
      float l2_0 = ftanh(l1_0 * l1_1);
      float l2_1 = ftanh(l1_2 + l1_3);
      float l2_2 = ftanh(l1_4 * l1_5);
      float l2_3 = fsig(l1_6 + l1_7);
      float l2_0b = ftanh(l2_0 + cp);
      float nc = l2_0b * l2_1;
      float l3_1 = ftanh(l2_2 + l2_3);
      float nm = ftanh(nc * l3_1);
      out_m[(size_t)grow * 1024 + h] = nm;
      out_c[(size_t)grow * 1024 + h] = nc;
    }
  }
}

// ---------------------------------------------------------------------------
// Legacy kernel (V1) — fallback when ws_size < 128 MB. Unchanged.
// ---------------------------------------------------------------------------
__global__ __launch_bounds__(256, 2) void nascell_main(
    const float* __restrict__ x,
    const float* __restrict__ m_prev,
    const float* __restrict__ c_prev,
    const float* __restrict__ w_inputs,
    const float* __restrict__ w_m,
    float* __restrict__ out) {
  __shared__ short lds[17408];
  const int tid = threadIdx.x;
  const int wid = tid >> 6;
  const int lane = tid & 63;
  const int row0 = blockIdx.y * 256;
  const int h0 = blockIdx.x * 16;
  const int m16 = lane & 15;
  const int q = lane >> 4;

  const int bmat = tid >> 7;
  const int bg = (tid >> 4) & 7;
  const int bkp = (tid & 15) * 2;
  const float* wsrc = bmat ? w_m : w_inputs;
  const float* wrow_base = wsrc + (size_t)bkp * 8192 + (size_t)bg * 1024 + (size_t)h0;
  short* bh = lds + bmat * 4352 + bg * 544 + (bkp ^ ((bg & 3) << 3));
  short* bl = bh + 8704;

  const float* axp[4];
  const float* amp[4];
#pragma unroll
  for (int r = 0; r < 4; ++r) {
    const size_t arow = (size_t)(row0 + wid * 64 + r * 16 + m16);
    axp[r] = x + arow * 1024 + q * 8;
    amp[r] = m_prev + arow * 1024 + q * 8;
  }

  f32x4 acc[4][9];
#pragma unroll
  for (int r = 0; r < 4; ++r)
#pragma unroll
    for (int gg = 0; gg < 9; ++gg) acc[r][gg] = (f32x4)0.0f;

  for (int kt = 0; kt < 32; ++kt) {
    const float* wr = wrow_base + (size_t)kt * 32 * 8192;
    float4v b0 = *(const float4v*)(wr);
    float4v b1 = *(const float4v*)(wr + 4);
    float4v b2 = *(const float4v*)(wr + 8);
    float4v b3 = *(const float4v*)(wr + 12);
    float4v d0 = *(const float4v*)(wr + 8192);
    float4v d1 = *(const float4v*)(wr + 8196);
    float4v d2 = *(const float4v*)(wr + 8200);
    float4v d3 = *(const float4v*)(wr + 8204);

    float4v xa[4][2];
#pragma unroll
    for (int r = 0; r < 4; ++r) {
      xa[r][0] = *(const float4v*)(axp[r] + kt * 32);
      xa[r][1] = *(const float4v*)(axp[r] + kt * 32 + 4);
    }

    __syncthreads();

#pragma unroll
    for (int n = 0; n < 16; ++n) {
      const float r0 = (n < 4 ? b0[n & 3] : n < 8 ? b1[n & 3] : n < 12 ? b2[n & 3] : b3[n & 3]);
      const float r1 = (n < 4 ? d0[n & 3] : n < 8 ? d1[n & 3] : n < 12 ? d2[n & 3] : d3[n & 3]);
      const _Float16 h0v = (_Float16)r0;
      const _Float16 h1v = (_Float16)r1;
      *(u32*)(bh + n * 32) = packh(h0v, h1v);
      const _Float16 l0v = (_Float16)(r0 - (float)h0v);
      const _Float16 l1v = (_Float16)(r1 - (float)h1v);
      *(u32*)(bl + n * 32) = packh(l0v, l1v);
    }

    half8 axh[4], axl[4];
#pragma unroll
    for (int r = 0; r < 4; ++r)
#pragma unroll
      for (int j = 0; j < 8; ++j) {
        const float v = xa[r][j >> 2][j & 3];
        const _Float16 hv = (_Float16)v;
        axh[r][j] = hv;
        axl[r][j] = (_Float16)(v - (float)hv);
      }

    __syncthreads();

    float4v ma[4][2];
#pragma unroll
    for (int r = 0; r < 4; ++r) {
      ma[r][0] = *(const float4v*)(amp[r] + kt * 32);
      ma[r][1] = *(const float4v*)(amp[r] + kt * 32 + 4);
    }

#pragma unroll
    for (int c = 0; c < 8; ++c) {
      const int qs = (q ^ (c & 3)) * 8;
      const int bo = c * 544 + m16 * 32 + qs;
      half8 bxh = *(const half8*)(lds + bo);
      half8 bxl = *(const half8*)(lds + 8704 + bo);
#pragma unroll
      for (int r = 0; r < 4; ++r) {
        f32x4 t = acc[r][c];
        t = __builtin_amdgcn_mfma_f32_16x16x32_f16(axh[r], bxh, t, 0, 0, 0);
        t = __builtin_amdgcn_mfma_f32_16x16x32_f16(axh[r], bxl, t, 0, 0, 0);
        t = __builtin_amdgcn_mfma_f32_16x16x32_f16(axl[r], bxh, t, 0, 0, 0);
        acc[r][c] = t;
      }
    }

    half8 amh[4], aml[4];
#pragma unroll
    for (int r = 0; r < 4; ++r)
#pragma unroll
      for (int j = 0; j < 8; ++j) {
        const float v = ma[r][j >> 2][j & 3];
        const _Float16 hv = (_Float16)v;
        amh[r][j] = hv;
        aml[r][j] = (_Float16)(v - (float)hv);
      }

#pragma unroll
    for (int c = 0; c < 8; ++c) {
      const int qs = (q ^ (c & 3)) * 8;
      const int bo = 4352 + c * 544 + m16 * 32 + qs;
      half8 bmh = *(const half8*)(lds + bo);
      half8 bml = *(const half8*)(lds + 8704 + bo);
      const int tgt = (c == 3) ? 8 : c;
#pragma unroll
      for (int r = 0; r < 4; ++r) {
        f32x4 t = acc[r][tgt];
        t = __builtin_amdgcn_mfma_f32_16x16x32_f16(amh[r], bmh, t, 0, 0, 0);
        t = __builtin_amdgcn_mfma_f32_16x16x32_f16(amh[r], bml, t, 0, 0, 0);
        t = __builtin_amdgcn_mfma_f32_16x16x32_f16(aml[r], bmh, t, 0, 0, 0);
        acc[r][tgt] = t;
      }
    }
  }

  float* out_m = out;
  float* out_c = out + (size_t)8192 * 1024;
  const int h = h0 + m16;
#pragma unroll
  for (int r = 0; r < 4; ++r) {
#pragma unroll
    for (int i = 0; i < 4; ++i) {
      const int grow = row0 + wid * 64 + r * 16 + q * 4 + i;
      const float p0 = acc[r][0][i], p1 = acc[r][1][i], p2 = acc[r][2][i];
      const float x3 = acc[r][3][i], p4 = acc[r][4][i], p5 = acc[r][5][i];
      const float p6 = acc[r][6][i], p7 = acc[r][7][i], m3 = acc[r][8][i];
      const float cp = c_prev[(size_t)grow * 1024 + h];
      float l1_0 = fsig(p0);
      float l1_1 = fmaxf(p1, 0.0f);
      float l1_2 = fsig(p2);
      float l1_3 = fmaxf(x3 * m3, 0.0f);
      float l1_4 = ftanh(p4);
      float l1_5 = fsig(p5);
      float l1_6 = ftanh(p6);
      float l1_7 = fsig(p7);
      float l2_0 = ftanh(l1_0 * l1_1);
      float l2_1 = ftanh(l1_2 + l1_3);
      float l2_2 = ftanh(l1_4 * l1_5);
      float l2_3 = fsig(l1_6 + l1_7);
      float l2_0b = ftanh(l2_0 + cp);
      float nc = l2_0b * l2_1;
      float l3_1 = ftanh(l2_2 + l2_3);
      float nm = ftanh(nc * l3_1);
      out_m[(size_t)grow * 1024 + h] = nm;
      out_c[(size_t)grow * 1024 + h] = nc;
    }
  }
}

extern "C" void kernel_launch(void* const* d_in, const int* in_sizes, int n_in,
                              void* d_out, int out_size, void* d_ws, size_t ws_size,
                              hipStream_t stream) {
  (void)in_sizes; (void)n_in; (void)out_size;
  const float* x        = (const float*)d_in[0];
  const float* m_prev   = (const float*)d_in[1];
  const float* c_prev   = (const float*)d_in[2];
  const float* w_m      = (const float*)d_in[3];
  const float* w_inputs = (const float*)d_in[4];
  float* out = (float*)d_out;

  // ws layout: [0,64MB) B half-tiles; then xh,xl,mh,ml (16MB each) = 128MB.
  if (ws_size >= 134217728ull && d_ws != nullptr) {
    u32* wsB = (u32*)d_ws;
    _Float16* xh = (_Float16*)((char*)d_ws + 67108864);
    _Float16* xl = xh + 8388608;
    _Float16* mh = xl + 8388608;
    _Float16* ml = mh + 8388608;
    prep_all<<<10240, 256, 0, stream>>>(
        w_inputs, w_m, (const float4v*)x, (const float4v*)m_prev, wsB,
        (half8*)xh, (half8*)xl, (half8*)mh, (half8*)ml);
    nascell_v7<<<dim3(32, 32), 512, 0, stream>>>(
        xh, xl, mh, ml, wsB, c_prev, out);
  } else {
    dim3 grid(64, 32);
    nascell_main<<<grid, 256, 0, stream>>>(x, m_prev, c_prev, w_inputs, w_m, out);
  }
}